// Round 8
// baseline (247.808 us; speedup 1.0000x reference)
//
#include <hip/hip_runtime.h>

// ts_zscore: rolling-window z-score
//   x: (B=64, T=4096, F=128) f32 ; out: (B=64, NK=4067, F=128) f32
//   out[b,k,f] = (x[b,k+29,f] - mean(x[b,k:k+30,f])) / (std(...) + 1e-4)
//
// R8: barrier-free per-wave streaming ring. R7 showed phase serialization
// (stage||compute never overlap; 8 block generations). Now each wave owns a
// 256-output stream with a private 6-slot LDS ring of 8-row granules staged
// via global_load_lds; counted s_waitcnt vmcnt(12) keeps 1-2 granules + the
// previous iteration's stores in flight at all times. No __syncthreads.
//   wait math (VMEM FIFO, in-issue-order retirement):
//   iter i needs granules <= i+4 complete; newest-12 = S(i-1)[8] + G(i+5)[4].

#define T_DIM   4096
#define F_DIM   128
#define NK      4067
#define L_OUT   256                    // outputs per wave-stream (32 iters x 8)
#define EPS_Z   1e-4f
#define SLAB_BYTES (T_DIM * 512)       // bytes per batch slab = 2,097,152
#define WAVE_LDS_F (6 * 1024)          // 6 slots * 4KB = 24KB per wave (floats)

__device__ __forceinline__ void gload_lds16(const float* g, float* l) {
    __builtin_amdgcn_global_load_lds(
        (const __attribute__((address_space(1))) void*)g,
        (__attribute__((address_space(3))) void*)l, 16, 0, 0);
}

__global__ __launch_bounds__(128)
void ts_zscore_kernel(const float* __restrict__ x, float* __restrict__ out) {
    extern __shared__ float smem[];    // 2 waves * 24KB

    int tid  = (int)threadIdx.x;
    int wave = tid >> 6;
    int lane = tid & 63;
    int ln2  = lane * 2;

    int gs = (int)blockIdx.x * 2 + wave;     // global stream id, 0..1023
    int b  = gs >> 4;                        // 16 streams per batch
    int s  = gs & 15;
    int k0 = s * L_OUT;
    if (k0 > NK - L_OUT) k0 = NK - L_OUT;    // overlap-pad (s=15 -> 3811)

    const float* xb = x + (size_t)b * (T_DIM * F_DIM);
    float*       ob = out + (size_t)b * (NK * F_DIM) + (size_t)k0 * F_DIM + ln2;
    float*       wl = smem + wave * WAVE_LDS_F;
    const int    k0b = k0 * 512;             // byte offset of stream base in slab

    // stage granule g (stream rows [8g,8g+8), 4KB) into ring slot sl.
    // Tail straddle fix: shift source AND dest back together by the overshoot
    // (multiple of 512B) -> needed rows keep correct positions; extra writes
    // duplicate already-correct data.
    auto stage = [&](int g, int sl) {
        #pragma unroll
        for (int j = 0; j < 4; ++j) {
            int bo = k0b + g * 4096 + j * 1024;
            int sh = bo + 1024 - SLAB_BYTES; sh = sh > 0 ? sh : 0;
            bo -= sh;
            gload_lds16(xb + (bo >> 2) + ln2 * 2,
                        wl + sl * 1024 + j * 256 - (sh >> 2));
        }
    };

    // ---- prologue: granules 0..5 into slots 0..5 (24 loads in flight)
    #pragma unroll
    for (int g = 0; g < 6; ++g) stage(g, g);
    asm volatile("s_waitcnt vmcnt(8)" ::: "memory");   // G0..G3 complete

    // ---- warm-up sums over stream rows 0..28 (granules 0..3)
    float s1x = 0.f, s1y = 0.f, s2x = 0.f, s2y = 0.f;
    #pragma unroll
    for (int r = 0; r < 29; ++r) {
        float2 v = *(const float2*)(wl + (r >> 3) * 1024 + (r & 7) * 128 + ln2);
        s1x += v.x;                 s1y += v.y;
        s2x = fmaf(v.x, v.x, s2x);  s2y = fmaf(v.y, v.y, s2y);
    }
    const float inv_w = 1.0f / 30.0f;

    asm volatile("s_waitcnt vmcnt(4)" ::: "memory");   // G4 complete (G5 in flight)

    // ring slots of granules i..i+5
    int c0 = 0, c1 = 1, c2 = 2, c3 = 3, c4 = 4, c5 = 5;

    for (int i = 0; i < 32; ++i) {
        if (i == 31)     { asm volatile("s_waitcnt vmcnt(0)"  ::: "memory"); }
        else if (i > 0)  { asm volatile("s_waitcnt vmcnt(12)" ::: "memory"); }

        // compute outputs [8i, 8i+8): old rows in granule i (slot c0),
        // new rows 8i+29..8i+36 split across granules i+3 (slot c3, rows 5..7)
        // and i+4 (slot c4, rows 0..4). All offsets compile-time per u.
        #pragma unroll
        for (int u = 0; u < 8; ++u) {
            const float2 v = *(const float2*)(wl +
                (u < 3 ? c3 * 1024 + (5 + u) * 128 : c4 * 1024 + (u - 3) * 128) + ln2);
            const float2 o = *(const float2*)(wl + c0 * 1024 + u * 128 + ln2);

            float t1x = s1x + v.x,            t1y = s1y + v.y;
            float t2x = fmaf(v.x, v.x, s2x),  t2y = fmaf(v.y, v.y, s2y);

            float mx = t1x * inv_w,  my = t1y * inv_w;
            float vx = fmaxf(fmaf(-mx, mx, t2x * inv_w), 0.f);
            float vy = fmaxf(fmaf(-my, my, t2y * inv_w), 0.f);

            *(float2*)(ob + (i * 8 + u) * F_DIM) = make_float2(
                __fdividef(v.x - mx, __fsqrt_rn(vx) + EPS_Z),
                __fdividef(v.y - my, __fsqrt_rn(vy) + EPS_Z));

            s1x = t1x - o.x;            s1y = t1y - o.y;
            s2x = fmaf(-o.x, o.x, t2x); s2y = fmaf(-o.y, o.y, t2y);
        }

        // refill granule i+6 into granule i's (now dead) slot, AFTER the
        // stores so the vmcnt count stays [stores(8), granule(4)] per iter.
        if (i <= 29) {
            __builtin_amdgcn_sched_barrier(0);
            stage(i + 6, c0);
        }
        int t = c0; c0 = c1; c1 = c2; c2 = c3; c3 = c4; c4 = c5; c5 = t;
    }
}

extern "C" void kernel_launch(void* const* d_in, const int* in_sizes, int n_in,
                              void* d_out, int out_size, void* d_ws, size_t ws_size,
                              hipStream_t stream) {
    const float* x = (const float*)d_in[0];
    float* out = (float*)d_out;
    dim3 grid(512);                 // 1024 wave-streams, single generation
    dim3 block(128);                // 2 waves/block, 48KB LDS -> >=2 blocks/CU
    ts_zscore_kernel<<<grid, block, 2 * WAVE_LDS_F * sizeof(float), stream>>>(x, out);
}

// Round 10
// 236.183 us; speedup vs baseline: 1.0492x; 1.0492x over previous
//
#include <hip/hip_runtime.h>

// ts_zscore: rolling-window z-score
//   x: (B=64, T=4096, F=128) f32 ; out: (B=64, NK=4067, F=128) f32
//   out[b,k,f] = (x[b,k+29,f] - mean(x[b,k:k+30,f])) / (std(...) + 1e-4)
//
// R9: R7 (best, 93us) + NONTEMPORAL STORES only (single-variable A/B).
// Unified model of R2-R8: all rounds ~= (bytes through L3) / ~3 TB/s --
// input is L3-warm, output L3-dirty (poison), so reads AND writes share the
// MALL path. nt stores (no-allocate) should push the 130MB write stream to
// HBM off the shared path -> reads/writes overlap instead of sharing.

#define B_DIM   64
#define T_DIM   4096
#define F_DIM   128
#define W_WIN   30
#define NK      4067               // T - W + 1
#define CH      128                // output rows per block
#define NCHUNK  32                 // ceil(NK/CH)
#define TROWS   157                // CH + W - 1 staged input rows
#define TILE_BYTES (TROWS * 512)   // 80,384 B  (2 blocks/CU: 160,768 <= 160 KiB)
#define ROUNDS  20                 // ceil(157 rows / 8 rows per 4KB round)
#define EPS_Z   1e-4f

__device__ __forceinline__ void gload_lds16(const float* g, float* l) {
    __builtin_amdgcn_global_load_lds(
        (const __attribute__((address_space(1))) void*)g,
        (__attribute__((address_space(3))) void*)l, 16, 0, 0);
}

__device__ __forceinline__ void nt_store_f2(float* p, float a, float b) {
    union { double d; float f[2]; } u;
    u.f[0] = a; u.f[1] = b;
    __builtin_nontemporal_store(u.d, (double*)p);   // global_store_dwordx2 ... nt
}

__global__ __launch_bounds__(256)
void ts_zscore_kernel(const float* __restrict__ x, float* __restrict__ out) {
    extern __shared__ float smem[];            // [157][128] floats, linear

    // bijective XCD swizzle: 2048 blocks % 8 == 0, 256 contiguous chunks/XCD
    int bid = (int)blockIdx.x;
    int cpx = (int)gridDim.x >> 3;             // 256
    int swz = (bid & 7) * cpx + (bid >> 3);    // adjacent chunks -> same XCD

    int b  = swz >> 5;                          // / NCHUNK
    int c  = swz & (NCHUNK - 1);
    int k0 = c * CH; if (k0 > NK - CH) k0 = NK - CH;   // overlap-pad tail

    int tid  = (int)threadIdx.x;
    int wave = tid >> 6;
    int lane = tid & 63;

    const float* xb = x + (size_t)b * T_DIM * F_DIM;

    // ---- stage rows [k0, k0+157) -> LDS. Per round: 4KB contiguous (8 rows),
    // each wave one 1KB global_load_lds_dwordx4 slice. All 20 rounds in flight.
    #pragma unroll
    for (int q = 0; q < ROUNDS; ++q) {
        int tb = q * 4096 + wave * 1024 + lane * 16;   // tile byte offset
        if (tb < TILE_BYTES) {                          // mask tail of round 19
            int r = k0 + (tb >> 9);                     // global row
            if (r > T_DIM - 1) r = T_DIM - 1;           // belt-and-braces
            const float* gp = xb + ((size_t)r << 7) + ((tb & 511) >> 2);
            float* lp = smem + q * 1024 + wave * 256;   // wave-uniform LDS base
            gload_lds16(gp, lp);
        }
    }
    __syncthreads();   // compiler drains vmcnt(0) before s_barrier

    // ---- compute: wave w owns outputs [k0+32w, k0+32w+32); inputs rows
    // [32w, 32w+61) of the LDS tile. Rolling sums, all reads from LDS.
    const float2* lrow = (const float2*)smem;   // row r, lane: lrow[r*64 + lane]
    int base = wave * 32;
    float* op = out + (size_t)b * NK * F_DIM
              + (size_t)(k0 + base) * F_DIM + lane * 2;

    float s1x = 0.f, s1y = 0.f, s2x = 0.f, s2y = 0.f;
    #pragma unroll
    for (int i = 0; i < 29; ++i) {
        float2 v = lrow[(base + i) * 64 + lane];
        s1x += v.x;                 s1y += v.y;
        s2x = fmaf(v.x, v.x, s2x);  s2y = fmaf(v.y, v.y, s2y);
    }

    const float inv_w = 1.0f / (float)W_WIN;

    #pragma unroll 8
    for (int ss = 0; ss < 32; ++ss) {
        float2 v = lrow[(base + 29 + ss) * 64 + lane];
        float2 o = lrow[(base + ss) * 64 + lane];

        float t1x = s1x + v.x,             t1y = s1y + v.y;
        float t2x = fmaf(v.x, v.x, s2x),   t2y = fmaf(v.y, v.y, s2y);

        float mx = t1x * inv_w,  my = t1y * inv_w;
        float vx = fmaxf(fmaf(-mx, mx, t2x * inv_w), 0.f);
        float vy = fmaxf(fmaf(-my, my, t2y * inv_w), 0.f);
        float ox = __fdividef(v.x - mx, __fsqrt_rn(vx) + EPS_Z);
        float oy = __fdividef(v.y - my, __fsqrt_rn(vy) + EPS_Z);
        nt_store_f2(op + ss * F_DIM, ox, oy);

        s1x = t1x - o.x;            s1y = t1y - o.y;
        s2x = fmaf(-o.x, o.x, t2x); s2y = fmaf(-o.y, o.y, t2y);
    }
}

extern "C" void kernel_launch(void* const* d_in, const int* in_sizes, int n_in,
                              void* d_out, int out_size, void* d_ws, size_t ws_size,
                              hipStream_t stream) {
    const float* x = (const float*)d_in[0];
    float* out = (float*)d_out;
    dim3 grid(B_DIM * NCHUNK);    // 2048 blocks, one 128-row chunk each
    dim3 block(256);
    ts_zscore_kernel<<<grid, block, TILE_BYTES, stream>>>(x, out);
}